// Round 12
// baseline (107.552 us; speedup 1.0000x reference)
//
#include <hip/hip_runtime.h>

// VQ-VAE VectorQuantizer fwd. K=1024, E=64, N=T*B=65536.
// bf16-split MFMA argmin (gap<6e-6 flagged) -> fp64 exact re-resolve.
// Scores t = ||c||^2 - 2 x.c; codebook pre-scaled by -2, ||c||^2 in C-init.
// MFMA: A = codebook frag, B = x frag -> D(lane l, reg r) =
// score(code = t*16 + (l>>4)*4 + r, row = base + (l&15)).
// R12: canonical LDS staging for the code stream. R4-R11 plateau (~35-50us)
// = per-wave codebook register traffic through thrashing L1 (4 disjoint
// 112KB streams vs 32KB L1). Now each block DMAs its K-quarter tile-by-tile
// into LDS (global_load_lds w16, 8KB padded records -> exactly 2 instrs/wave
// -> uniform vmcnt(2)), T3 2-phase pipeline with raw s_barrier + counted
// vmcnt; all 4 waves ds_read from LDS (256B/cyc, lockstep).
// Also: SSE via identity d^2 = score + ||x||^2 (rx2 from argmin, summed in
// k_merge) -> k_output is a pure gather (no x re-read); histogram in
// k_merge, k_exact64 adjusts counts on idx change.

#define KC 1024
#define ED 64
#define NR 65536
#define NE (NR * ED)
#define GAP1 6e-6f

typedef __attribute__((ext_vector_type(8))) short short8;
typedef __attribute__((ext_vector_type(4))) float f32x4;

__device__ __forceinline__ unsigned short bf16rne(float f) {
    unsigned u = __builtin_bit_cast(unsigned, f);
    return (unsigned short)((u + 0x7fffu + ((u >> 16) & 1u)) >> 16);
}
__device__ __forceinline__ float bf16tof(unsigned short h) {
    return __builtin_bit_cast(float, (unsigned)h << 16);
}

#define GLOAD_LDS16(GSRC, LDST) \
    __builtin_amdgcn_global_load_lds( \
        (const __attribute__((address_space(1))) void*)(GSRC), \
        (__attribute__((address_space(3))) void*)(LDST), 16, 0, 0)

// Pack 8KB-padded tile records + zero counts/flag. Record t (short8 stride
// 512): j=0..5 codebook fragments of -2*c (chunks [ch e0-31|ch e32-63|
// cl e0-31|cl e32-63|ch e0-31|ch e32-63], paired at MFMA with x chunks
// [xh0|xh1|xh0|xh1|xl0|xl1]; elem (g=l>>4,r) <-> k-slot g*8+r, same
// bijection both operands); j=6: f32x4 ||c||^2 C-init (reg r <-> code
// t*16+(l>>4)*4+r) bitcast short8; [448,512) pad (staged, never read).
__global__ __launch_bounds__(256) void k_pack(const float* __restrict__ cb,
        short8* __restrict__ cbt, unsigned* __restrict__ counts,
        unsigned* __restrict__ flagcnt) {
    const int u = blockIdx.x * 256 + threadIdx.x;
    if (u < 1024) counts[u] = 0u;
    if (u == 1024) *flagcnt = 0u;
    if (u >= 64 * 7 * 64) return;
    const int t = u / 448, rem = u % 448, j = rem / 64, l = rem % 64;
    const int g = l >> 4;
    const int w = t * 512 + j * 64 + l;
    if (j < 6) {
        const int code = t * 16 + (l & 15);
        const float* c = cb + (size_t)code * ED;
        short8 o;
#pragma unroll
        for (int r = 0; r < 8; ++r) {
            const int k = j * 32 + g * 8 + r;
            int e; bool lo;
            if (j < 2)      { e = k;       lo = false; }
            else if (j < 4) { e = k - 64;  lo = true;  }
            else            { e = k - 128; lo = false; }
            const float m2 = -2.f * c[e];
            const unsigned short h = bf16rne(m2);
            o[r] = lo ? (short)bf16rne(m2 - bf16tof(h)) : (short)h;
        }
        cbt[w] = o;
    } else {
        f32x4 o;
#pragma unroll
        for (int r = 0; r < 4; ++r) {
            const float4* c4 = (const float4*)(cb + (size_t)(t * 16 + g * 4 + r) * ED);
            float s0 = 0.f, s1 = 0.f, s2 = 0.f, s3 = 0.f;
#pragma unroll
            for (int i = 0; i < 16; ++i) {
                const float4 c = c4[i];
                s0 = fmaf(c.x, c.x, s0); s1 = fmaf(c.y, c.y, s1);
                s2 = fmaf(c.z, c.z, s2); s3 = fmaf(c.w, c.w, s3);
            }
            o[r] = (s0 + s1) + (s2 + s3);
        }
        cbt[w] = __builtin_bit_cast(short8, o);
    }
}

// grid = 256 row-groups x 4 K-splits = 1024 blocks x 256 thr (4 waves).
// Block owns 256 rows (wave wid owns 64), scans tiles [ks*16, ks*16+16).
// Tiles staged to LDS double-buffer via global_load_lds (2 instrs/wave/tile,
// uniform), vmcnt(2) + raw barrier per tile (counted, never drained mid-loop
// except last). x hi/lo frags converted once into regs; ||x||^2 (rx2)
// written by ks==0 blocks. Partial top-2 per row -> pb/pb2/pk[row*4+ks].
__global__ __launch_bounds__(256) void k_argmin_part(
        const float* __restrict__ in, const short8* __restrict__ cbt,
        float* __restrict__ pb, float* __restrict__ pb2, int* __restrict__ pk,
        float* __restrict__ rx2) {
    __shared__ short8 lbuf[2][512];               // 2 x 8KB

    const int tid = threadIdx.x;
    const int l = tid & 63;
    const int wid = tid >> 6;                     // 0..3
    const int g = l >> 4;
    const int col = l & 15;
    const int ks = blockIdx.x & 3;
    const int rowBase = (blockIdx.x >> 2) * 256 + wid * 64;
    const int t0 = ks * 16;

    // Prologue: stage tile t0 into lbuf[0] (2 x 1KB segments per wave).
    {
        const short8* src = cbt + (size_t)t0 * 512;
#pragma unroll
        for (int i = wid; i < 8; i += 4)
            GLOAD_LDS16(src + i * 64 + l, &lbuf[0][i * 64]);
    }

    // Convert x -> bf16 hi/lo frags in regs (overlaps the DMA), + ||x||^2.
    short8 xq[4][4];
#pragma unroll
    for (int rt = 0; rt < 4; ++rt) {
        const int row = rowBase + rt * 16 + col;
        float s2 = 0.f;
#pragma unroll
        for (int h = 0; h < 2; ++h) {
            short8 H, L;
#pragma unroll
            for (int j = 0; j < 8; ++j) {
                const float x = in[(size_t)(h * 32 + g * 8 + j) * NR + row];
                const unsigned short hb = bf16rne(x);
                H[j] = (short)hb;
                L[j] = (short)bf16rne(x - bf16tof(hb));
                s2 = fmaf(x, x, s2);
            }
            xq[rt][h] = H; xq[rt][2 + h] = L;
        }
        float s = s2;
        s += __shfl_xor(s, 16, 64);
        s += __shfl_xor(s, 32, 64);
        if (ks == 0 && g == 0) rx2[row] = s;
    }

    asm volatile("s_waitcnt vmcnt(0)" ::: "memory");
    __builtin_amdgcn_s_barrier();

    float best[4]  = {3.4e38f, 3.4e38f, 3.4e38f, 3.4e38f};
    float best2[4] = {3.4e38f, 3.4e38f, 3.4e38f, 3.4e38f};
    int bestk[4] = {0, 0, 0, 0};

    for (int tt = 0; tt < 16; ++tt) {
        const int cur = tt & 1;
        if (tt < 15) {
            const short8* src = cbt + (size_t)(t0 + tt + 1) * 512;
#pragma unroll
            for (int i = wid; i < 8; i += 4)
                GLOAD_LDS16(src + i * 64 + l, &lbuf[cur ^ 1][i * 64]);
            asm volatile("s_waitcnt vmcnt(2)" ::: "memory"); // cur's 2 landed
        } else {
            asm volatile("s_waitcnt vmcnt(0)" ::: "memory");
        }
        __builtin_amdgcn_s_barrier();                        // tile cur ready

        const short8 b0 = lbuf[cur][0 * 64 + l], b1 = lbuf[cur][1 * 64 + l],
                     b2 = lbuf[cur][2 * 64 + l], b3 = lbuf[cur][3 * 64 + l],
                     b4 = lbuf[cur][4 * 64 + l], b5 = lbuf[cur][5 * 64 + l];
        const f32x4 e4 = __builtin_bit_cast(f32x4, lbuf[cur][384 + l]);
        const int t = t0 + tt;
#pragma unroll
        for (int rt = 0; rt < 4; ++rt) {
            f32x4 acc = e4;
            acc = __builtin_amdgcn_mfma_f32_16x16x32_bf16(b0, xq[rt][0], acc, 0, 0, 0);
            acc = __builtin_amdgcn_mfma_f32_16x16x32_bf16(b1, xq[rt][1], acc, 0, 0, 0);
            acc = __builtin_amdgcn_mfma_f32_16x16x32_bf16(b2, xq[rt][0], acc, 0, 0, 0);
            acc = __builtin_amdgcn_mfma_f32_16x16x32_bf16(b3, xq[rt][1], acc, 0, 0, 0);
            acc = __builtin_amdgcn_mfma_f32_16x16x32_bf16(b4, xq[rt][2], acc, 0, 0, 0);
            acc = __builtin_amdgcn_mfma_f32_16x16x32_bf16(b5, xq[rt][3], acc, 0, 0, 0);
#pragma unroll
            for (int r = 0; r < 4; ++r) {
                const float v = acc[r];
                const int k = t * 16 + g * 4 + r;
                best2[rt] = fminf(fmaxf(v, best[rt]), best2[rt]);  // med3
                const bool c = v < best[rt];
                bestk[rt] = c ? k : bestk[rt];
                best[rt]  = fminf(v, best[rt]);
            }
        }
        __builtin_amdgcn_s_barrier();              // protect buf overwrite
    }

    // g-merge via shfl; g==0 lanes write the K-split partials.
#pragma unroll
    for (int rt = 0; rt < 4; ++rt) {
        float b = best[rt], b2 = best2[rt]; int k = bestk[rt];
#pragma unroll
        for (int sh = 16; sh <= 32; sh <<= 1) {
            const float ob  = __shfl_xor(b, sh, 64);
            const float ob2 = __shfl_xor(b2, sh, 64);
            const int   ok  = __shfl_xor(k, sh, 64);
            if (ob < b || (ob == b && ok < k)) { b2 = fminf(b, ob2); k = ok; b = ob; }
            else b2 = fminf(b2, ob);
        }
        if (g == 0) {
            const int row = rowBase + rt * 16 + col;
            pb[row * 4 + ks] = b; pb2[row * 4 + ks] = b2; pk[row * 4 + ks] = k;
        }
    }
}

// Merge 4 K-split partials per row; idx + flag + histogram + SSE partial
// (sse_row = best + ||x||^2; fp64 block reduce -> pblk[bid], fixed order).
__global__ __launch_bounds__(256) void k_merge(
        const float* __restrict__ pb, const float* __restrict__ pb2,
        const int* __restrict__ pk, const float* __restrict__ rx2,
        int* __restrict__ idx, unsigned* __restrict__ counts,
        unsigned* __restrict__ flagcnt, unsigned* __restrict__ flaglist,
        double* __restrict__ pblk) {
    __shared__ double sred[4];
    const int n = blockIdx.x * 256 + threadIdx.x;
    float b = pb[n * 4], b2 = pb2[n * 4]; int k = pk[n * 4];
#pragma unroll
    for (int s = 1; s < 4; ++s) {                   // ascending k ranges
        const float ob = pb[n * 4 + s], ob2 = pb2[n * 4 + s];
        const int ok = pk[n * 4 + s];
        if (ob < b || (ob == b && ok < k)) { b2 = fminf(b, ob2); k = ok; b = ob; }
        else b2 = fminf(b2, ob);
    }
    idx[n] = k;
    atomicAdd(&counts[k], 1u);
    if (b2 - b < GAP1) {
        const unsigned p = atomicAdd(flagcnt, 1u);
        flaglist[p] = (unsigned)n;
    }
    double ld = (double)b + (double)rx2[n];         // d^2 = score + ||x||^2
#pragma unroll
    for (int off = 32; off > 0; off >>= 1) ld += __shfl_down(ld, off, 64);
    if ((threadIdx.x & 63) == 0) sred[threadIdx.x >> 6] = ld;
    __syncthreads();
    if (threadIdx.x == 0)
        pblk[blockIdx.x] = (sred[0] + sred[1]) + (sred[2] + sred[3]);
}

// fp64 exact argmin for flagged rows; one wave per row; adjusts histogram
// when the index changes. (SSE delta < GAP1 per flipped row -> negligible.)
__global__ __launch_bounds__(256) void k_exact64(
        const float* __restrict__ in, const float* __restrict__ cb,
        int* __restrict__ idx, unsigned* __restrict__ counts,
        const unsigned* __restrict__ flagcnt, const unsigned* __restrict__ flaglist) {
    const unsigned nf = *flagcnt;
    const int l = threadIdx.x & 63;
    const unsigned wave = blockIdx.x * 4u + (unsigned)(threadIdx.x >> 6);
    const unsigned nwave = gridDim.x * 4u;
    for (unsigned i = wave; i < nf; i += nwave) {
        const int row = (int)flaglist[i];
        float x[ED];
#pragma unroll
        for (int e = 0; e < ED; ++e) x[e] = in[(size_t)e * NR + row];
        double best = 1e300; int bestk = 0;
        for (int ci = 0; ci < 16; ++ci) {
            const int k = ci * 64 + l;              // ascending k per lane
            const float* c = cb + (size_t)k * ED;
            double s = 0.0, e2 = 0.0;
            for (int e = 0; e < ED; ++e) {
                const double cv = (double)c[e];
                e2 = fma(cv, cv, e2);
                s  = fma(cv, (double)x[e], s);
            }
            const double t = fma(-2.0, s, e2);
            if (t < best) { best = t; bestk = k; }
        }
        for (int sh = 1; sh < 64; sh <<= 1) {
            const double ob = __shfl_xor(best, sh, 64);
            const int   ok  = __shfl_xor(bestk, sh, 64);
            if (ob < best || (ob == best && ok < bestk)) { best = ob; bestk = ok; }
        }
        if (l == 0) {
            const int old = idx[row];
            if (bestk != old) {
                idx[row] = bestk;
                atomicSub(&counts[old], 1u);
                atomicAdd(&counts[bestk], 1u);
            }
        }
    }
}

// Pure gather: qout[e][n] = cb[idx[n]][e]. No x read, no atomics.
__global__ __launch_bounds__(256) void k_output(
        const float* __restrict__ cb, const int* __restrict__ idx,
        float* __restrict__ qout) {
    const int gtid = blockIdx.x * 256 + threadIdx.x;
    const int n = gtid & (NR - 1);
    const int e0 = gtid >> 16;                      // 0..7
    const int k = idx[n];
    const float4* c4 = (const float4*)(cb + (size_t)k * ED + e0 * 8);
    const float4 q0 = c4[0], q1 = c4[1];
#pragma unroll
    for (int j = 0; j < 8; ++j) {
        const float q = (j < 4) ? ((const float*)&q0)[j] : ((const float*)&q1)[j - 4];
        qout[(size_t)(e0 * 8 + j) * NR + n] = q;
    }
}

// Final: entropy from counts (post-exact64) + SSE from 256 merge partials.
__global__ __launch_bounds__(1024) void k_final(const unsigned* __restrict__ counts,
        const double* __restrict__ pblk, float* __restrict__ out) {
    __shared__ double redE[16], redS[16];
    const int tid = threadIdx.x;
    const double p = (double)counts[tid] * (1.0 / 65536.0);
    double term = p * log(p + 1e-10);
    double s = (tid < 256) ? pblk[tid] : 0.0;
#pragma unroll
    for (int off = 32; off > 0; off >>= 1) {
        term += __shfl_down(term, off, 64);
        s    += __shfl_down(s,    off, 64);
    }
    if ((tid & 63) == 0) { redE[tid >> 6] = term; redS[tid >> 6] = s; }
    __syncthreads();
    if (tid == 0) {
        double e = 0.0, ss = 0.0;
        for (int i = 0; i < 16; ++i) { e += redE[i]; ss += redS[i]; }
        out[1 + NE] = (float)exp(-e);                 // perplexity
        const double m = ss * (1.0 / 4194304.0);      // mean((q-x)^2)
        out[0] = (float)(1.25 * m);                   // (1+beta)*m
    }
}

extern "C" void kernel_launch(void* const* d_in, const int* in_sizes, int n_in,
                              void* d_out, int out_size, void* d_ws, size_t ws_size,
                              hipStream_t stream) {
    (void)in_sizes; (void)n_in; (void)out_size; (void)ws_size;
    const float* in = (const float*)d_in[0];
    const float* cb = (const float*)d_in[1];
    float* out = (float*)d_out;

    // ws layout (dword offsets), strictly disjoint:
    //  [0,1024) counts | [1024] flagcnt
    //  [2048,133120)   cbt: 64 tiles x 512 short8 (8KB padded records)
    //  [133120,395264) pb | [395264,657408) pb2 | [657408,919552) pk
    //  [919552,985088) idx | [985088,1050624) flaglist
    //  [1050624,1116160) rx2 | pblk: 256 f64 at byte 4464640 (8B-aligned)
    unsigned* counts   = (unsigned*)d_ws;
    unsigned* flagcnt  = (unsigned*)d_ws + 1024;
    short8*   cbt      = (short8*)((float*)d_ws + 2048);
    float*    pb       = (float*)d_ws + 133120;
    float*    pb2      = (float*)d_ws + 395264;
    int*      pk       = (int*)d_ws + 657408;
    int*      idx      = (int*)d_ws + 919552;
    unsigned* flaglist = (unsigned*)d_ws + 985088;
    float*    rx2      = (float*)d_ws + 1050624;
    double*   pblk     = (double*)((char*)d_ws + 4464640);

    hipLaunchKernelGGL(k_pack,        dim3(112),  dim3(256),  0, stream,
                       cb, cbt, counts, flagcnt);
    hipLaunchKernelGGL(k_argmin_part, dim3(1024), dim3(256),  0, stream,
                       in, cbt, pb, pb2, pk, rx2);
    hipLaunchKernelGGL(k_merge,       dim3(256),  dim3(256),  0, stream,
                       pb, pb2, pk, rx2, idx, counts, flagcnt, flaglist, pblk);
    hipLaunchKernelGGL(k_exact64,     dim3(128),  dim3(256),  0, stream,
                       in, cb, idx, counts, flagcnt, flaglist);
    hipLaunchKernelGGL(k_output,      dim3(2048), dim3(256),  0, stream,
                       cb, idx, out + 1);
    hipLaunchKernelGGL(k_final,       dim3(1),    dim3(1024), 0, stream,
                       counts, pblk, out);
}

// Round 13
// 90.117 us; speedup vs baseline: 1.1935x; 1.1935x over previous
//
#include <hip/hip_runtime.h>

// VQ-VAE VectorQuantizer fwd. K=1024, E=64, N=T*B=65536.
// bf16-split MFMA argmin (gap<6e-6 flagged) -> fp64 exact re-resolve.
// Scores t = ||c||^2 - 2 x.c; codebook pre-scaled by -2, ||c||^2 in C-init.
// MFMA: A = codebook frag, B = x frag -> D(lane l, reg r) =
// score(code = t*16 + (l>>4)*4 + r, row = base + (l&15)).
// R13: rows-per-wave 64 -> 128 halves codebook register traffic (448->224MB,
// the 1/rpw lever); conversion-once per block (R9/R11 lesson, R12 broke it);
// full pipeline fused: argmin block does idx+histogram+flag+SSE (d^2 = best
// + ||x||^2) -> no k_merge; k_final fused into k_output block 0. 4 launches.
// 256 blocks x 512 thr = 2 row-groups x 4 K-quarters; ~205 VGPR target, no
// launch_bounds min-waves arg (forces 64-VGPR spill, R5/R7).

#define KC 1024
#define ED 64
#define NR 65536
#define NE (NR * ED)
#define GAP1 6e-6f

typedef __attribute__((ext_vector_type(8))) short short8;
typedef __attribute__((ext_vector_type(4))) float f32x4;

__device__ __forceinline__ unsigned short bf16rne(float f) {
    unsigned u = __builtin_bit_cast(unsigned, f);
    return (unsigned short)((u + 0x7fffu + ((u >> 16) & 1u)) >> 16);
}
__device__ __forceinline__ float bf16tof(unsigned short h) {
    return __builtin_bit_cast(float, (unsigned)h << 16);
}

// Pack compact tile records (stride 448 short8) + zero counts/flag.
// Record t: j=0..5 codebook frags of -2*c (chunks [ch e0-31|ch e32-63|
// cl e0-31|cl e32-63|ch e0-31|ch e32-63], paired at MFMA with x chunks
// [xh0|xh1|xh0|xh1|xl0|xl1]; elem (g=l>>4,r) <-> k-slot g*8+r, same
// bijection both operands); j=6: f32x4 ||c||^2 (reg r <-> code
// t*16+(l>>4)*4+r) bitcast short8.
__global__ __launch_bounds__(256) void k_pack(const float* __restrict__ cb,
        short8* __restrict__ cbt, unsigned* __restrict__ counts,
        unsigned* __restrict__ flagcnt) {
    const int u = blockIdx.x * 256 + threadIdx.x;
    if (u < 1024) counts[u] = 0u;
    if (u == 1024) *flagcnt = 0u;
    if (u >= 64 * 7 * 64) return;
    const int t = u / 448, rem = u % 448, j = rem / 64, l = rem % 64;
    const int g = l >> 4;
    if (j < 6) {
        const int code = t * 16 + (l & 15);
        const float* c = cb + (size_t)code * ED;
        short8 o;
#pragma unroll
        for (int r = 0; r < 8; ++r) {
            const int k = j * 32 + g * 8 + r;
            int e; bool lo;
            if (j < 2)      { e = k;       lo = false; }
            else if (j < 4) { e = k - 64;  lo = true;  }
            else            { e = k - 128; lo = false; }
            const float m2 = -2.f * c[e];
            const unsigned short h = bf16rne(m2);
            o[r] = lo ? (short)bf16rne(m2 - bf16tof(h)) : (short)h;
        }
        cbt[u] = o;
    } else {
        f32x4 o;
#pragma unroll
        for (int r = 0; r < 4; ++r) {
            const float4* c4 = (const float4*)(cb + (size_t)(t * 16 + g * 4 + r) * ED);
            float s0 = 0.f, s1 = 0.f, s2 = 0.f, s3 = 0.f;
#pragma unroll
            for (int i = 0; i < 16; ++i) {
                const float4 c = c4[i];
                s0 = fmaf(c.x, c.x, s0); s1 = fmaf(c.y, c.y, s1);
                s2 = fmaf(c.z, c.z, s2); s3 = fmaf(c.w, c.w, s3);
            }
            o[r] = (s0 + s1) + (s2 + s3);
        }
        cbt[u] = __builtin_bit_cast(short8, o);
    }
}

// 256 blocks x 512 thr (8 waves = 2 row-groups x 4 K-quarters). Block owns
// 256 rows. Phase 1: cooperative x -> bf16 hi/lo frags into LDS (coalesced,
// once) + ||x||^2 partials. Phase 2: wave (rg=wid>>2, kh=wid&3) holds its
// 128 rows' frags in 128 VGPR, scans tiles [kh*16,+16). Phase 3: shfl
// g-merge; waves 0-3 merge across kh (ascending == k-ascending tie-break),
// write idx, histogram, flag, and fp64 SSE partial (d^2 = best + ||x||^2).
__global__ __launch_bounds__(512) void k_argmin(
        const float* __restrict__ in, const short8* __restrict__ cbt,
        int* __restrict__ idx, unsigned* __restrict__ counts,
        unsigned* __restrict__ flagcnt, unsigned* __restrict__ flaglist,
        double* __restrict__ pblk) {
    __shared__ short8 xs[16][4][64];              // 64 KB
    __shared__ float rx2p[2][256];                // 2 KB
    __shared__ float sb[4][16][16], sb2[4][16][16];
    __shared__ int   sk[4][16][16];               // 12 KB
    __shared__ double sred[4];

    const int tid = threadIdx.x;
    const int l = tid & 63;
    const int wid = tid >> 6;                     // 0..7
    const int g = l >> 4;
    const int col = l & 15;
    const int rowBase = blockIdx.x * 256;

    // Phase 1: thread (row=tid&255, h=tid>>8) converts e-range [h*32,+32)
    // of its row into 4 hi + 4 lo short8 (one per g), + Sum x^2 partial.
    {
        const int row = tid & 255;
        const int h = tid >> 8;                   // 0..1
        const int grt = row >> 4;
        const int cl = row & 15;
        float part = 0.f;
#pragma unroll
        for (int gg = 0; gg < 4; ++gg) {
            short8 H, L;
#pragma unroll
            for (int j = 0; j < 8; ++j) {
                const float x = in[(size_t)(h * 32 + gg * 8 + j) * NR + rowBase + row];
                const unsigned short hb = bf16rne(x);
                H[j] = (short)hb;
                L[j] = (short)bf16rne(x - bf16tof(hb));
                part = fmaf(x, x, part);
            }
            xs[grt][h][gg * 16 + cl] = H;
            xs[grt][2 + h][gg * 16 + cl] = L;
        }
        rx2p[h][row] = part;
    }
    __syncthreads();

    // Phase 2: stage 128 rows' frags to regs, scan this K-quarter.
    const int rg = wid >> 2, kh = wid & 3;
    short8 xq[8][4];
#pragma unroll
    for (int rt = 0; rt < 8; ++rt)
#pragma unroll
        for (int q = 0; q < 4; ++q)
            xq[rt][q] = xs[rg * 8 + rt][q][l];

    float best[8], best2[8]; int bestk[8];
#pragma unroll
    for (int rt = 0; rt < 8; ++rt) { best[rt] = 3.4e38f; best2[rt] = 3.4e38f; bestk[rt] = 0; }

    for (int tt = 0; tt < 16; ++tt) {
        const int t = kh * 16 + tt;
        const short8* bp = cbt + (size_t)t * 448 + l;
        const short8 b0 = bp[0], b1 = bp[64], b2 = bp[128],
                     b3 = bp[192], b4 = bp[256], b5 = bp[320];
        const f32x4 e4 = __builtin_bit_cast(f32x4, bp[384]);
#pragma unroll
        for (int rt = 0; rt < 8; ++rt) {
            f32x4 acc = e4;
            acc = __builtin_amdgcn_mfma_f32_16x16x32_bf16(b0, xq[rt][0], acc, 0, 0, 0);
            acc = __builtin_amdgcn_mfma_f32_16x16x32_bf16(b1, xq[rt][1], acc, 0, 0, 0);
            acc = __builtin_amdgcn_mfma_f32_16x16x32_bf16(b2, xq[rt][0], acc, 0, 0, 0);
            acc = __builtin_amdgcn_mfma_f32_16x16x32_bf16(b3, xq[rt][1], acc, 0, 0, 0);
            acc = __builtin_amdgcn_mfma_f32_16x16x32_bf16(b4, xq[rt][2], acc, 0, 0, 0);
            acc = __builtin_amdgcn_mfma_f32_16x16x32_bf16(b5, xq[rt][3], acc, 0, 0, 0);
#pragma unroll
            for (int r = 0; r < 4; ++r) {
                const float v = acc[r];
                const int k = t * 16 + g * 4 + r;
                best2[rt] = fminf(fmaxf(v, best[rt]), best2[rt]);  // med3
                const bool c = v < best[rt];
                bestk[rt] = c ? k : bestk[rt];
                best[rt]  = fminf(v, best[rt]);
            }
        }
    }

    // Phase 3a: intra-wave g-merge; g==0 writes per-(kh, grt) partials.
#pragma unroll
    for (int rt = 0; rt < 8; ++rt) {
        float b = best[rt], b2 = best2[rt]; int k = bestk[rt];
#pragma unroll
        for (int sh = 16; sh <= 32; sh <<= 1) {
            const float ob  = __shfl_xor(b, sh, 64);
            const float ob2 = __shfl_xor(b2, sh, 64);
            const int   ok  = __shfl_xor(k, sh, 64);
            if (ob < b || (ob == b && ok < k)) { b2 = fminf(b, ob2); k = ok; b = ob; }
            else b2 = fminf(b2, ob);
        }
        if (g == 0) {
            sb[kh][rg * 8 + rt][col] = b;
            sb2[kh][rg * 8 + rt][col] = b2;
            sk[kh][rg * 8 + rt][col] = k;
        }
    }
    __syncthreads();

    // Phase 3b: waves 0-3 merge kh slices; finalize row outputs.
    if (wid < 4) {
        const int grt = wid * 4 + (l >> 4);
        float b = sb[0][grt][col], b2 = sb2[0][grt][col]; int k = sk[0][grt][col];
#pragma unroll
        for (int s = 1; s < 4; ++s) {              // ascending k ranges
            const float ob = sb[s][grt][col], ob2 = sb2[s][grt][col];
            const int ok = sk[s][grt][col];
            if (ob < b || (ob == b && ok < k)) { b2 = fminf(b, ob2); k = ok; b = ob; }
            else b2 = fminf(b2, ob);
        }
        const int lrow = grt * 16 + col;
        const int row = rowBase + lrow;
        idx[row] = k;
        atomicAdd(&counts[k], 1u);
        if (b2 - b < GAP1) {
            const unsigned p = atomicAdd(flagcnt, 1u);
            flaglist[p] = (unsigned)row;
        }
        double d2 = (double)b + (double)(rx2p[0][lrow] + rx2p[1][lrow]);
#pragma unroll
        for (int off = 32; off > 0; off >>= 1) d2 += __shfl_down(d2, off, 64);
        if (l == 0) sred[wid] = d2;
    }
    __syncthreads();
    if (tid == 0)
        pblk[blockIdx.x] = (sred[0] + sred[1]) + (sred[2] + sred[3]);
}

// fp64 exact argmin for flagged rows; one wave per row; adjusts histogram
// when the index changes. (SSE delta < GAP1 per flipped row -> negligible.)
__global__ __launch_bounds__(256) void k_exact64(
        const float* __restrict__ in, const float* __restrict__ cb,
        int* __restrict__ idx, unsigned* __restrict__ counts,
        const unsigned* __restrict__ flagcnt, const unsigned* __restrict__ flaglist) {
    const unsigned nf = *flagcnt;
    const int l = threadIdx.x & 63;
    const unsigned wave = blockIdx.x * 4u + (unsigned)(threadIdx.x >> 6);
    const unsigned nwave = gridDim.x * 4u;
    for (unsigned i = wave; i < nf; i += nwave) {
        const int row = (int)flaglist[i];
        float x[ED];
#pragma unroll
        for (int e = 0; e < ED; ++e) x[e] = in[(size_t)e * NR + row];
        double best = 1e300; int bestk = 0;
        for (int ci = 0; ci < 16; ++ci) {
            const int k = ci * 64 + l;              // ascending k per lane
            const float* c = cb + (size_t)k * ED;
            double s = 0.0, e2 = 0.0;
            for (int e = 0; e < ED; ++e) {
                const double cv = (double)c[e];
                e2 = fma(cv, cv, e2);
                s  = fma(cv, (double)x[e], s);
            }
            const double t = fma(-2.0, s, e2);
            if (t < best) { best = t; bestk = k; }
        }
        for (int sh = 1; sh < 64; sh <<= 1) {
            const double ob = __shfl_xor(best, sh, 64);
            const int   ok  = __shfl_xor(bestk, sh, 64);
            if (ob < best || (ob == best && ok < bestk)) { best = ob; bestk = ok; }
        }
        if (l == 0) {
            const int old = idx[row];
            if (bestk != old) {
                idx[row] = bestk;
                atomicSub(&counts[old], 1u);
                atomicAdd(&counts[bestk], 1u);
            }
        }
    }
}

// Gather qout[e][n] = cb[idx[n]][e]; block 0 additionally computes the two
// scalar outputs (entropy from counts, SSE from 256 pblk partials) -- both
// finalized before this launch (fix64 ran), fixed-order -> deterministic.
__global__ __launch_bounds__(256) void k_output(
        const float* __restrict__ cb, const int* __restrict__ idx,
        float* __restrict__ qout, const unsigned* __restrict__ counts,
        const double* __restrict__ pblk, float* __restrict__ out) {
    const int gtid = blockIdx.x * 256 + threadIdx.x;
    const int n = gtid & (NR - 1);
    const int e0 = gtid >> 16;                      // 0..7
    const int k = idx[n];
    const float4* c4 = (const float4*)(cb + (size_t)k * ED + e0 * 8);
    const float4 q0 = c4[0], q1 = c4[1];
#pragma unroll
    for (int j = 0; j < 8; ++j) {
        const float q = (j < 4) ? ((const float*)&q0)[j] : ((const float*)&q1)[j - 4];
        qout[(size_t)(e0 * 8 + j) * NR + n] = q;
    }
    if (blockIdx.x == 0) {
        __shared__ double redE[4], redS[4];
        const int tid = threadIdx.x;
        double term = 0.0;
#pragma unroll
        for (int i = 0; i < 4; ++i) {
            const double p = (double)counts[tid + i * 256] * (1.0 / 65536.0);
            term += p * log(p + 1e-10);
        }
        double s = pblk[tid];
#pragma unroll
        for (int off = 32; off > 0; off >>= 1) {
            term += __shfl_down(term, off, 64);
            s    += __shfl_down(s,    off, 64);
        }
        if ((tid & 63) == 0) { redE[tid >> 6] = term; redS[tid >> 6] = s; }
        __syncthreads();
        if (tid == 0) {
            const double e = (redE[0] + redE[1]) + (redE[2] + redE[3]);
            const double ss = (redS[0] + redS[1]) + (redS[2] + redS[3]);
            out[1 + NE] = (float)exp(-e);             // perplexity
            const double m = ss * (1.0 / 4194304.0);  // mean((q-x)^2)
            out[0] = (float)(1.25 * m);               // (1+beta)*m
        }
    }
}

extern "C" void kernel_launch(void* const* d_in, const int* in_sizes, int n_in,
                              void* d_out, int out_size, void* d_ws, size_t ws_size,
                              hipStream_t stream) {
    (void)in_sizes; (void)n_in; (void)out_size; (void)ws_size;
    const float* in = (const float*)d_in[0];
    const float* cb = (const float*)d_in[1];
    float* out = (float*)d_out;

    // ws layout (dword offsets), strictly disjoint:
    //  [0,1024) counts | [1024] flagcnt
    //  [2048,116736)   cbt: 64 tiles x 448 short8 (compact 7KB records)
    //  [116736,182272) idx | [182272,247808) flaglist
    //  pblk: 256 f64 at byte 991232 (8B-aligned)
    unsigned* counts   = (unsigned*)d_ws;
    unsigned* flagcnt  = (unsigned*)d_ws + 1024;
    short8*   cbt      = (short8*)((float*)d_ws + 2048);
    int*      idx      = (int*)d_ws + 116736;
    unsigned* flaglist = (unsigned*)d_ws + 182272;
    double*   pblk     = (double*)((char*)d_ws + 991232);

    hipLaunchKernelGGL(k_pack,    dim3(112),  dim3(256), 0, stream,
                       cb, cbt, counts, flagcnt);
    hipLaunchKernelGGL(k_argmin,  dim3(256),  dim3(512), 0, stream,
                       in, cbt, idx, counts, flagcnt, flaglist, pblk);
    hipLaunchKernelGGL(k_exact64, dim3(128),  dim3(256), 0, stream,
                       in, cb, idx, counts, flagcnt, flaglist);
    hipLaunchKernelGGL(k_output,  dim3(2048), dim3(256), 0, stream,
                       cb, idx, out + 1, counts, pblk, out);
}